// Round 6
// baseline (34.742 us; speedup 1.0000x reference)
//
#include <hip/hip_runtime.h>

#define NROWS 4096
#define NCOLS 6144
#define TPB   256

typedef float f32x4 __attribute__((ext_vector_type(4)));

// Semantics (verbatim from reference):
//   r_loss  = mean |sigmoid(p)-t| over rows ≡0 mod 3  (1366 rows × 6144 cols)
//   t_loss  = mean |sigmoid(p)-t| over rows ≡1 mod 3  (1365 rows × 6144 cols)
//   phi     = sum over ALL rows, cols with col%3==2 AND col<4096 of
//             min(|x|,|x-1|,|x+1|), x = sigmoid(p)-t; divided by 4096*2048.
//             Since x∈[-1,1]: min(|x|,|x-1|,|x+1|) == min(|x|, 1-|x|).
// Rows ≡2 mod 3 contribute only phi (cols<4096) -> load only chunks k<4.
//
// R6 structure test: 4096 one-shot 1-row blocks (16 blocks/CU of work, 8
// resident + 8 backfill) so per-CU outstanding-load concurrency is refilled
// as blocks retire, instead of the R4/R5 grid==capacity sawtooth (issue 24,
// drain to 0, no refill -> avg concurrency ~half, straggler tail).

#define GLOAD(dst, ptr) \
    asm volatile("global_load_dwordx4 %0, %1, off" : "=v"(dst) : "v"(ptr))
#define WAITV(N) do { \
    asm volatile("s_waitcnt vmcnt(" #N ")"); \
    __builtin_amdgcn_sched_barrier(0); } while (0)

// BKT 0: accumulate |sigmoid-t| into asum (+phi if K<4); BKT 2: phi only.
template<int K, int BKT>
__device__ __forceinline__ void chunk(f32x4 p, f32x4 t, int tidm3,
                                      float& asum, float& psum) {
#pragma unroll
    for (int j = 0; j < 4; ++j) {
        const float e = __expf(-p[j]);
        const float s = __builtin_amdgcn_rcpf(1.0f + e);   // sigmoid
        const float x = s - t[j];
        const float a = fabsf(x);
        if (BKT != 2) asum += a;
        if (K < 4) {                       // col < 4096 ⟺ k < 4 (compile-time)
            const float d = fminf(a, 1.0f - a);            // circular dist
            const int want = ((2 - K - j) % 3 + 3) % 3;    // col%3==2 ⟺ tid%3==want
            psum += (tidm3 == want) ? d : 0.0f;
        }
    }
}

__global__ void __launch_bounds__(256)
spherical_main(const f32x4* __restrict__ preds,
               const f32x4* __restrict__ targs,
               float* __restrict__ pr, float* __restrict__ pt,
               float* __restrict__ pp) {
    const int row = blockIdx.x;
    const int tid = threadIdx.x;
    const f32x4* pA = preds + (size_t)row * (NCOLS / 4) + tid;
    const f32x4* tA = targs + (size_t)row * (NCOLS / 4) + tid;
    const int tidm3 = tid % 3;
    const int kind  = row % 3;             // wave-uniform

    float asum = 0.f, ps = 0.f;

    if (kind != 2) {                       // full row: 12 loads in flight
        f32x4 P[6], T[6];
        GLOAD(P[0], pA + 0*TPB); GLOAD(T[0], tA + 0*TPB);
        GLOAD(P[1], pA + 1*TPB); GLOAD(T[1], tA + 1*TPB);
        GLOAD(P[2], pA + 2*TPB); GLOAD(T[2], tA + 2*TPB);
        GLOAD(P[3], pA + 3*TPB); GLOAD(T[3], tA + 3*TPB);
        GLOAD(P[4], pA + 4*TPB); GLOAD(T[4], tA + 4*TPB);
        GLOAD(P[5], pA + 5*TPB); GLOAD(T[5], tA + 5*TPB);
        WAITV(10); chunk<0,0>(P[0], T[0], tidm3, asum, ps);
        WAITV(8);  chunk<1,0>(P[1], T[1], tidm3, asum, ps);
        WAITV(6);  chunk<2,0>(P[2], T[2], tidm3, asum, ps);
        WAITV(4);  chunk<3,0>(P[3], T[3], tidm3, asum, ps);
        WAITV(2);  chunk<4,0>(P[4], T[4], tidm3, asum, ps);
        WAITV(0);  chunk<5,0>(P[5], T[5], tidm3, asum, ps);
    } else {                               // phi-only row: cols<4096, 8 loads
        f32x4 P[4], T[4];
        GLOAD(P[0], pA + 0*TPB); GLOAD(T[0], tA + 0*TPB);
        GLOAD(P[1], pA + 1*TPB); GLOAD(T[1], tA + 1*TPB);
        GLOAD(P[2], pA + 2*TPB); GLOAD(T[2], tA + 2*TPB);
        GLOAD(P[3], pA + 3*TPB); GLOAD(T[3], tA + 3*TPB);
        WAITV(6);  chunk<0,2>(P[0], T[0], tidm3, asum, ps);
        WAITV(4);  chunk<1,2>(P[1], T[1], tidm3, asum, ps);
        WAITV(2);  chunk<2,2>(P[2], T[2], tidm3, asum, ps);
        WAITV(0);  chunk<3,2>(P[3], T[3], tidm3, asum, ps);
    }

    // 64-lane wave reduction, then cross-wave via LDS
#pragma unroll
    for (int off = 32; off > 0; off >>= 1) {
        asum += __shfl_down(asum, off);
        ps   += __shfl_down(ps, off);
    }
    __shared__ float la[4], lp[4];
    const int wave = tid >> 6, lane = tid & 63;
    if (lane == 0) { la[wave] = asum; lp[wave] = ps; }
    __syncthreads();
    if (tid == 0) {
        const float ba = la[0] + la[1] + la[2] + la[3];
        pr[row] = (kind == 0) ? ba : 0.f;  // every slot written every call
        pt[row] = (kind == 1) ? ba : 0.f;
        pp[row] = lp[0] + lp[1] + lp[2] + lp[3];
    }
}

__global__ void __launch_bounds__(1024)
spherical_final(const float* __restrict__ pr, const float* __restrict__ pt,
                const float* __restrict__ pp, float* __restrict__ out) {
    const int tid = threadIdx.x;
    double sr = 0.0, st = 0.0, sp = 0.0;
    for (int i = tid; i < NROWS; i += 1024) {   // fixed order -> deterministic
        sr += (double)pr[i]; st += (double)pt[i]; sp += (double)pp[i];
    }
#pragma unroll
    for (int off = 32; off > 0; off >>= 1) {
        sr += __shfl_down(sr, off);
        st += __shfl_down(st, off);
        sp += __shfl_down(sp, off);
    }
    __shared__ double dr[16], dt[16], dp[16];
    const int wave = tid >> 6, lane = tid & 63;
    if (lane == 0) { dr[wave] = sr; dt[wave] = st; dp[wave] = sp; }
    __syncthreads();
    if (tid == 0) {
        double r = 0.0, t = 0.0, p = 0.0;
#pragma unroll
        for (int w = 0; w < 16; ++w) { r += dr[w]; t += dt[w]; p += dp[w]; }
        r /= 1366.0 * 6144.0;
        t /= 1365.0 * 6144.0;
        p /= 4096.0 * 2048.0;
        out[0] = (float)(r + t + p);
        out[1] = (float)r;
        out[2] = (float)t;
        out[3] = (float)p;
    }
}

extern "C" void kernel_launch(void* const* d_in, const int* in_sizes, int n_in,
                              void* d_out, int out_size, void* d_ws, size_t ws_size,
                              hipStream_t stream) {
    const f32x4* preds = (const f32x4*)d_in[0];
    const f32x4* targs = (const f32x4*)d_in[1];
    float* pr = (float*)d_ws;        // 4096 floats
    float* pt = pr + NROWS;          // 4096 floats
    float* pp = pt + NROWS;          // 4096 floats (48 KB total)

    spherical_main<<<dim3(NROWS), dim3(TPB), 0, stream>>>(preds, targs, pr, pt, pp);
    spherical_final<<<dim3(1), dim3(1024), 0, stream>>>(pr, pt, pp, (float*)d_out);
}